// Round 8
// baseline (61.097 us; speedup 1.0000x reference)
//
#include <hip/hip_runtime.h>

#define HC 256
#define WC 256
#define CC 96
#define BB 4
#define OH 258
#define OW 258
#define PLANE 65536
#define NPAIR 128                    // 256 r-rows as 128 pairs
#define K2_JOBS (BB * 9 * OH)        // 9288 (one wave per out row)
#define K2_BLOCKS ((K2_JOBS + 3) / 4)
#define SZH ((size_t)BB * 9 * PLANE * 4)   // bytes per r-half: 9.44 MB

__device__ __forceinline__ float4 ld4(const float* p){ return *reinterpret_cast<const float4*>(p); }
__device__ __forceinline__ void st4(float* p, float4 v){ *reinterpret_cast<float4*>(p) = v; }

// acc[A..C] = d0..d0+2 (ti=0,1,2); window w0..w5 = x2 cols 4t-1 .. 4t+4
__device__ __forceinline__ void tap6(float4& A, float4& B, float4& C, const float4 a,
                                     float w0, float w1, float w2, float w3, float w4, float w5)
{
    A.x = fmaf(a.x, w0, A.x); A.y = fmaf(a.y, w1, A.y); A.z = fmaf(a.z, w2, A.z); A.w = fmaf(a.w, w3, A.w);
    B.x = fmaf(a.x, w1, B.x); B.y = fmaf(a.y, w2, B.y); B.z = fmaf(a.z, w3, B.z); B.w = fmaf(a.w, w4, B.w);
    C.x = fmaf(a.x, w2, C.x); C.y = fmaf(a.y, w3, C.y); C.z = fmaf(a.z, w4, C.z); C.w = fmaf(a.w, w5, C.w);
}

// ---------------- kernel 1: partial r over CC/NH channels per block ----------------
// wave = full 256-wide row-pair (h0,h1) x (24/NH) channels; block = 4 waves.
// grid (NPAIR, NH, BB); half = blockIdx.y writes rws + half*SZH/4 floats.
template<int NH>
__global__ __launch_bounds__(256) void corr_r_kernel(
    const float* __restrict__ x1, const float* __restrict__ x2, float* __restrict__ rws)
{
    constexpr int CGW = 24 / NH;     // channels per wave
    const int tid = threadIdx.x;
    const int g   = tid >> 6;        // wave id 0..3
    const int t   = tid & 63;        // quad-col: cols 4t..4t+3
    const int pair = blockIdx.x;
    const int half = blockIdx.y;
    const int b    = blockIdx.z;
    const int h0 = 2 * pair, h1 = h0 + 1;
    const int wq = 4 * t;

    const bool vm1 = (h0 > 0);
    const bool vp2 = (h1 < HC - 1);
    const int rm1 = vm1 ? h0 - 1 : 0;
    const int rp2 = vp2 ? h1 + 1 : HC - 1;

    const int c0 = half * (CC / NH) + g * CGW;
    const float* p1c = x1 + (size_t)(b * CC + c0) * PLANE;
    const float* p2c = x2 + (size_t)(b * CC + c0) * PLANE;

    const int o1a = h0 * WC + wq, o1b = h1 * WC + wq;
    const int o20 = rm1 * WC + wq, o21 = h0 * WC + wq, o22 = h1 * WC + wq, o23 = rp2 * WC + wq;

    const float4 fz = make_float4(0.f, 0.f, 0.f, 0.f);
    float4 acc0[9], acc1[9];
#pragma unroll
    for (int d = 0; d < 9; ++d) { acc0[d] = fz; acc1[d] = fz; }

    float4 a0 = ld4(p1c + o1a), a1 = ld4(p1c + o1b);
    float4 q0 = vm1 ? ld4(p2c + o20) : fz;
    float4 q1 = ld4(p2c + o21);
    float4 q2 = ld4(p2c + o22);
    float4 q3 = vp2 ? ld4(p2c + o23) : fz;

#define COMPUTE_STEP()                                                         \
    do {                                                                       \
        float pw0 = __shfl_up(q0.w, 1), nx0 = __shfl_down(q0.x, 1);            \
        float pw1 = __shfl_up(q1.w, 1), nx1 = __shfl_down(q1.x, 1);            \
        float pw2 = __shfl_up(q2.w, 1), nx2 = __shfl_down(q2.x, 1);            \
        float pw3 = __shfl_up(q3.w, 1), nx3 = __shfl_down(q3.x, 1);            \
        if (t == 0)  { pw0 = 0; pw1 = 0; pw2 = 0; pw3 = 0; }                   \
        if (t == 63) { nx0 = 0; nx1 = 0; nx2 = 0; nx3 = 0; }                   \
        tap6(acc0[0], acc0[1], acc0[2], a0, pw0, q0.x, q0.y, q0.z, q0.w, nx0); \
        tap6(acc0[3], acc0[4], acc0[5], a0, pw1, q1.x, q1.y, q1.z, q1.w, nx1); \
        tap6(acc1[0], acc1[1], acc1[2], a1, pw1, q1.x, q1.y, q1.z, q1.w, nx1); \
        tap6(acc0[6], acc0[7], acc0[8], a0, pw2, q2.x, q2.y, q2.z, q2.w, nx2); \
        tap6(acc1[3], acc1[4], acc1[5], a1, pw2, q2.x, q2.y, q2.z, q2.w, nx2); \
        tap6(acc1[6], acc1[7], acc1[8], a1, pw3, q3.x, q3.y, q3.z, q3.w, nx3); \
    } while (0)

    for (int c = 0; c < CGW - 1; ++c) {
        p1c += PLANE; p2c += PLANE;
        float4 na0 = ld4(p1c + o1a), na1 = ld4(p1c + o1b);
        float4 nq0 = vm1 ? ld4(p2c + o20) : fz;
        float4 nq1 = ld4(p2c + o21);
        float4 nq2 = ld4(p2c + o22);
        float4 nq3 = vp2 ? ld4(p2c + o23) : fz;
        COMPUTE_STEP();
        a0 = na0; a1 = na1; q0 = nq0; q1 = nq1; q2 = nq2; q3 = nq3;
    }
    COMPUTE_STEP();
#undef COMPUTE_STEP

    // ---- reduce the 4 waves' partials in LDS (contiguous float4 rows: conflict-free) ----
    __shared__ __align__(16) float red[9][2][WC];   // 18432 B
    for (int r = 0; r < 4; ++r) {
        if (g == r) {
#pragma unroll
            for (int d = 0; d < 9; ++d) {
                float* d0p = &red[d][0][wq];
                float* d1p = &red[d][1][wq];
                if (r == 0) { st4(d0p, acc0[d]); st4(d1p, acc1[d]); }
                else {
                    float4 v0 = ld4(d0p), v1 = ld4(d1p);
                    v0.x += acc0[d].x; v0.y += acc0[d].y; v0.z += acc0[d].z; v0.w += acc0[d].w;
                    v1.x += acc1[d].x; v1.y += acc1[d].y; v1.z += acc1[d].z; v1.w += acc1[d].w;
                    st4(d0p, v0); st4(d1p, v1);
                }
            }
        }
        __syncthreads();
    }

    // ---- write r rows (h0,h1): rws[half][b][d][h][w] ----
    float* dst = rws + (size_t)half * (BB * 9) * PLANE;
    for (int idx = tid; idx < 9 * 2 * 64; idx += 256) {
        const int t2 = idx & 63;
        const int ds = idx >> 6;
        const int s  = ds & 1;
        const int d  = ds >> 1;
        float4 v = ld4(&red[d][s][4 * t2]);
        st4(dst + (((size_t)(b * 9 + d) * HC) + (h0 + s)) * WC + 4 * t2, v);
    }
}

// ---------------- kernel 2: out = (1/864) * 3x3 box over (sum of NH halves of r) ----------------
// one wave per (b,d,y); lanes = quad-cols; left halo via shfl; lane 63 also emits cols 256,257.
template<int NH>
__global__ __launch_bounds__(256) void corr_box_kernel(
    const float* __restrict__ rws, float* __restrict__ out)
{
    const int tid = threadIdx.x;
    const int wid = tid >> 6, t = tid & 63;
    const int job = blockIdx.x * 4 + wid;
    if (job >= K2_JOBS) return;
    const int y  = job % OH;
    const int bd = job / OH;
    const float* rp0 = rws + (size_t)bd * PLANE;
    const float* rp1 = rws + (size_t)(BB * 9) * PLANE + (size_t)bd * PLANE;

    float4 s4 = make_float4(0.f, 0.f, 0.f, 0.f);
    float s256 = 0.f, s257 = 0.f;
#pragma unroll
    for (int k = 0; k < 3; ++k) {
        const int rr = y - 2 + k;
        if ((unsigned)rr < (unsigned)HC) {
            float4 q = ld4(rp0 + rr * WC + 4 * t);
            if (NH == 2) {
                float4 q2 = ld4(rp1 + rr * WC + 4 * t);
                q.x += q2.x; q.y += q2.y; q.z += q2.z; q.w += q2.w;
            }
            float pz = __shfl_up(q.z, 1);
            float pw = __shfl_up(q.w, 1);
            if (t == 0) { pz = 0.f; pw = 0.f; }
            s4.x += pz + pw + q.x;
            s4.y += pw + q.x + q.y;
            s4.z += q.x + q.y + q.z;
            s4.w += q.y + q.z + q.w;
            s256 += q.z + q.w;   // out col 256: r cols 254,255
            s257 += q.w;         // out col 257: r col 255
        }
    }
    float* orow = out + ((size_t)bd * OH + y) * OW;
    const float sc = 1.0f / 864.0f;
    orow[4 * t]     = s4.x * sc;
    orow[4 * t + 1] = s4.y * sc;
    orow[4 * t + 2] = s4.z * sc;
    orow[4 * t + 3] = s4.w * sc;
    if (t == 63) { orow[256] = s256 * sc; orow[257] = s257 * sc; }
}

extern "C" void kernel_launch(void* const* d_in, const int* in_sizes, int n_in,
                              void* d_out, int out_size, void* d_ws, size_t ws_size,
                              hipStream_t stream) {
    const float* x1 = (const float*)d_in[0];
    const float* x2 = (const float*)d_in[1];
    float* out = (float*)d_out;
    float* rws = (float*)d_ws;
    if (ws_size >= 2 * SZH) {
        hipLaunchKernelGGL((corr_r_kernel<2>), dim3(NPAIR, 2, BB), dim3(256), 0, stream, x1, x2, rws);
        hipLaunchKernelGGL((corr_box_kernel<2>), dim3(K2_BLOCKS), dim3(256), 0, stream, rws, out);
    } else {
        // proven R7 path (ws >= 9.44 MB verified on this harness)
        hipLaunchKernelGGL((corr_r_kernel<1>), dim3(NPAIR, 1, BB), dim3(256), 0, stream, x1, x2, rws);
        hipLaunchKernelGGL((corr_box_kernel<1>), dim3(K2_BLOCKS), dim3(256), 0, stream, rws, out);
    }
}

// Round 9
// 43.104 us; speedup vs baseline: 1.4174x; 1.4174x over previous
//
#include <hip/hip_runtime.h>

#define HC 256
#define WC 256
#define CC 96
#define BB 4
#define OH 258
#define OW 258
#define PLANE 65536
#define NPAIR 128                    // 256 r-rows as 128 pairs
#define CGW 24                       // channels per wave (4 waves/block)
#define K2_JOBS (BB * 9 * OH)        // 9288 (one wave per out row)
#define K2_BLOCKS ((K2_JOBS + 3) / 4)
#define WS_NEEDED ((size_t)BB * 9 * PLANE * 4)   // 9.44 MB of r

__device__ __forceinline__ float4 ld4(const float* p){ return *reinterpret_cast<const float4*>(p); }
__device__ __forceinline__ void st4(float* p, float4 v){ *reinterpret_cast<float4*>(p) = v; }

// acc[A..C] = d0..d0+2 (ti=0,1,2); window w0..w5 = x2 cols 4t-1 .. 4t+4
__device__ __forceinline__ void tap6(float4& A, float4& B, float4& C, const float4 a,
                                     float w0, float w1, float w2, float w3, float w4, float w5)
{
    A.x = fmaf(a.x, w0, A.x); A.y = fmaf(a.y, w1, A.y); A.z = fmaf(a.z, w2, A.z); A.w = fmaf(a.w, w3, A.w);
    B.x = fmaf(a.x, w1, B.x); B.y = fmaf(a.y, w2, B.y); B.z = fmaf(a.z, w3, B.z); B.w = fmaf(a.w, w4, B.w);
    C.x = fmaf(a.x, w2, C.x); C.y = fmaf(a.y, w3, C.y); C.z = fmaf(a.z, w4, C.z); C.w = fmaf(a.w, w5, C.w);
}

// ---------------- kernel 1: r(h,w,d) = sum_c x1[c,h,w]*x2[c,h+tj-1,w+ti-1] ----------------
// wave = full 256-wide row-pair (h0,h1) x 24 channels; block = 4 waves = 4 channel groups.
// Depth-2 channel prefetch (two register slots); XCD-chunked pair mapping for halo L2 reuse.
__global__ __launch_bounds__(256) void corr_r_kernel(
    const float* __restrict__ x1, const float* __restrict__ x2, float* __restrict__ rws)
{
    const int tid = threadIdx.x;
    const int g   = tid >> 6;        // wave id / channel group 0..3
    const int t   = tid & 63;        // quad-col: cols 4t..4t+3
    // XCD-chunked: adjacent pairs (sharing x2 halo rows) on the same XCD's L2.
    const int bid  = blockIdx.x;                 // 0..127
    const int pair = (bid & 7) * (NPAIR / 8) + (bid >> 3);
    const int b    = blockIdx.y;
    const int h0 = 2 * pair, h1 = h0 + 1;
    const int wq = 4 * t;

    const bool vm1 = (h0 > 0);
    const bool vp2 = (h1 < HC - 1);
    const int rm1 = vm1 ? h0 - 1 : 0;
    const int rp2 = vp2 ? h1 + 1 : HC - 1;

    const float* p1b = x1 + (size_t)(b * CC + g * CGW) * PLANE;
    const float* p2b = x2 + (size_t)(b * CC + g * CGW) * PLANE;

    const int o1a = h0 * WC + wq, o1b = h1 * WC + wq;
    const int o20 = rm1 * WC + wq, o21 = h0 * WC + wq, o22 = h1 * WC + wq, o23 = rp2 * WC + wq;

    const float4 fz = make_float4(0.f, 0.f, 0.f, 0.f);
    float4 acc0[9], acc1[9];
#pragma unroll
    for (int d = 0; d < 9; ++d) { acc0[d] = fz; acc1[d] = fz; }

    // two prefetch slots (depth-2 pipeline)
    float4 A0[2], A1[2], Q0[2], Q1[2], Q2[2], Q3[2];

#define ISSUE(s, cc)                                                           \
    do {                                                                       \
        const float* P1 = p1b + (size_t)(cc) * PLANE;                          \
        const float* P2 = p2b + (size_t)(cc) * PLANE;                          \
        A0[s] = ld4(P1 + o1a);                                                 \
        A1[s] = ld4(P1 + o1b);                                                 \
        Q0[s] = vm1 ? ld4(P2 + o20) : fz;                                      \
        Q1[s] = ld4(P2 + o21);                                                 \
        Q2[s] = ld4(P2 + o22);                                                 \
        Q3[s] = vp2 ? ld4(P2 + o23) : fz;                                      \
    } while (0)

#define COMPUTE_STEP(s)                                                                          \
    do {                                                                                         \
        float pw0 = __shfl_up(Q0[s].w, 1), nx0 = __shfl_down(Q0[s].x, 1);                        \
        float pw1 = __shfl_up(Q1[s].w, 1), nx1 = __shfl_down(Q1[s].x, 1);                        \
        float pw2 = __shfl_up(Q2[s].w, 1), nx2 = __shfl_down(Q2[s].x, 1);                        \
        float pw3 = __shfl_up(Q3[s].w, 1), nx3 = __shfl_down(Q3[s].x, 1);                        \
        if (t == 0)  { pw0 = 0; pw1 = 0; pw2 = 0; pw3 = 0; }                                     \
        if (t == 63) { nx0 = 0; nx1 = 0; nx2 = 0; nx3 = 0; }                                     \
        tap6(acc0[0], acc0[1], acc0[2], A0[s], pw0, Q0[s].x, Q0[s].y, Q0[s].z, Q0[s].w, nx0);    \
        tap6(acc0[3], acc0[4], acc0[5], A0[s], pw1, Q1[s].x, Q1[s].y, Q1[s].z, Q1[s].w, nx1);    \
        tap6(acc1[0], acc1[1], acc1[2], A1[s], pw1, Q1[s].x, Q1[s].y, Q1[s].z, Q1[s].w, nx1);    \
        tap6(acc0[6], acc0[7], acc0[8], A0[s], pw2, Q2[s].x, Q2[s].y, Q2[s].z, Q2[s].w, nx2);    \
        tap6(acc1[3], acc1[4], acc1[5], A1[s], pw2, Q2[s].x, Q2[s].y, Q2[s].z, Q2[s].w, nx2);    \
        tap6(acc1[6], acc1[7], acc1[8], A1[s], pw3, Q3[s].x, Q3[s].y, Q3[s].z, Q3[s].w, nx3);    \
    } while (0)

    ISSUE(0, 0);
    ISSUE(1, 1);
#pragma unroll 2
    for (int c = 0; c < CGW; ++c) {
        const int s = c & 1;
        COMPUTE_STEP(s);
        if (c + 2 < CGW) ISSUE(s, c + 2);
    }
#undef ISSUE
#undef COMPUTE_STEP

    // ---- reduce the 4 waves' partials in LDS (contiguous float4 rows: conflict-free) ----
    __shared__ __align__(16) float red[9][2][WC];   // 18432 B
    for (int r = 0; r < 4; ++r) {
        if (g == r) {
#pragma unroll
            for (int d = 0; d < 9; ++d) {
                float* d0p = &red[d][0][wq];
                float* d1p = &red[d][1][wq];
                if (r == 0) { st4(d0p, acc0[d]); st4(d1p, acc1[d]); }
                else {
                    float4 v0 = ld4(d0p), v1 = ld4(d1p);
                    v0.x += acc0[d].x; v0.y += acc0[d].y; v0.z += acc0[d].z; v0.w += acc0[d].w;
                    v1.x += acc1[d].x; v1.y += acc1[d].y; v1.z += acc1[d].z; v1.w += acc1[d].w;
                    st4(d0p, v0); st4(d1p, v1);
                }
            }
        }
        __syncthreads();
    }

    // ---- write r rows (h0,h1) to workspace: rws[b][d][h][w] ----
    for (int idx = tid; idx < 9 * 2 * 64; idx += 256) {
        const int t2 = idx & 63;
        const int ds = idx >> 6;
        const int s  = ds & 1;
        const int d  = ds >> 1;
        float4 v = ld4(&red[d][s][4 * t2]);
        st4(rws + (((size_t)(b * 9 + d) * HC) + (h0 + s)) * WC + 4 * t2, v);
    }
}

// ---------------- kernel 2: out = (1/864) * 3x3 box over r ----------------
// one wave per (b,d,y); lanes = quad-cols; left halo via shfl; lane 63 also emits cols 256,257.
__global__ __launch_bounds__(256) void corr_box_kernel(
    const float* __restrict__ rws, float* __restrict__ out)
{
    const int tid = threadIdx.x;
    const int wid = tid >> 6, t = tid & 63;
    const int job = blockIdx.x * 4 + wid;
    if (job >= K2_JOBS) return;
    const int y  = job % OH;
    const int bd = job / OH;
    const float* rp = rws + (size_t)bd * PLANE;

    float4 s4 = make_float4(0.f, 0.f, 0.f, 0.f);
    float s256 = 0.f, s257 = 0.f;
#pragma unroll
    for (int k = 0; k < 3; ++k) {
        const int rr = y - 2 + k;
        if ((unsigned)rr < (unsigned)HC) {
            float4 q = ld4(rp + rr * WC + 4 * t);
            float pz = __shfl_up(q.z, 1);
            float pw = __shfl_up(q.w, 1);
            if (t == 0) { pz = 0.f; pw = 0.f; }
            s4.x += pz + pw + q.x;
            s4.y += pw + q.x + q.y;
            s4.z += q.x + q.y + q.z;
            s4.w += q.y + q.z + q.w;
            s256 += q.z + q.w;   // out col 256: r cols 254,255
            s257 += q.w;         // out col 257: r col 255
        }
    }
    float* orow = out + ((size_t)bd * OH + y) * OW;
    const float sc = 1.0f / 864.0f;
    orow[4 * t]     = s4.x * sc;
    orow[4 * t + 1] = s4.y * sc;
    orow[4 * t + 2] = s4.z * sc;
    orow[4 * t + 3] = s4.w * sc;
    if (t == 63) { orow[256] = s256 * sc; orow[257] = s257 * sc; }
}

// ---------------- fallback (ws too small): Round-0 verified kernel ----------------
#define FBTOX 30
#define FBTOY 14
__global__ __launch_bounds__(256) void corr2d_fb(
    const float* __restrict__ x1, const float* __restrict__ x2, float* __restrict__ out)
{
    const int tx = threadIdx.x, ty = threadIdx.y;
    const int bx = blockIdx.x, by = blockIdx.y, b = blockIdx.z;
    const int x0 = bx * FBTOX, y0 = by * FBTOY;
    const int w = x0 - 2 + tx;
    const int h0 = y0 - 2 + ty, h1 = h0 + 8;
    const size_t plane = (size_t)HC * WC;
    const float* p1 = x1 + (size_t)b * CC * plane;
    const float* p2 = x2 + (size_t)b * CC * plane;
    float acc[2][9];
#pragma unroll
    for (int i = 0; i < 2; ++i)
#pragma unroll
        for (int d = 0; d < 9; ++d) acc[i][d] = 0.f;
    const bool interior = (x0 >= 3) && (x0 + 30 <= WC - 1) && (y0 >= 3) && (y0 + 14 <= HC - 1);
    if (interior) {
        const float* q1 = p1 + (size_t)(h0 * WC + w);
        const float* q2 = p2 + (size_t)(h0 * WC + w);
        for (int c = 0; c < CC; ++c) {
            const float a0 = q1[0];
            const float a1 = q1[8 * WC];
#pragma unroll
            for (int tj = -1; tj <= 1; ++tj)
#pragma unroll
                for (int ti = -1; ti <= 1; ++ti) {
                    const int d = (tj + 1) * 3 + (ti + 1);
                    acc[0][d] = fmaf(a0, q2[tj * WC + ti], acc[0][d]);
                    acc[1][d] = fmaf(a1, q2[(tj + 8) * WC + ti], acc[1][d]);
                }
            q1 += plane; q2 += plane;
        }
    } else {
        int rows[6]; bool rv[6];
        const int hh[6] = {h0 - 1, h0, h0 + 1, h1 - 1, h1, h1 + 1};
#pragma unroll
        for (int j = 0; j < 6; ++j) {
            rv[j] = ((unsigned)hh[j] < (unsigned)HC);
            int hcl = hh[j] < 0 ? 0 : (hh[j] > HC - 1 ? HC - 1 : hh[j]);
            rows[j] = hcl * WC;
        }
        int cols[3]; bool cv[3];
#pragma unroll
        for (int i = 0; i < 3; ++i) {
            int ww = w - 1 + i;
            cv[i] = ((unsigned)ww < (unsigned)WC);
            cols[i] = ww < 0 ? 0 : (ww > WC - 1 ? WC - 1 : ww);
        }
        const bool v0 = ((unsigned)h0 < (unsigned)HC) && ((unsigned)w < (unsigned)WC);
        const bool v1 = ((unsigned)h1 < (unsigned)HC) && ((unsigned)w < (unsigned)WC);
        const int wcl = w < 0 ? 0 : (w > WC - 1 ? WC - 1 : w);
        const int off1_0 = (h0 < 0 ? 0 : (h0 > HC - 1 ? HC - 1 : h0)) * WC + wcl;
        const int off1_1 = (h1 < 0 ? 0 : (h1 > HC - 1 ? HC - 1 : h1)) * WC + wcl;
        const float* q1 = p1;
        const float* q2 = p2;
        for (int c = 0; c < CC; ++c) {
            const float a0 = v0 ? q1[off1_0] : 0.f;
            const float a1 = v1 ? q1[off1_1] : 0.f;
#pragma unroll
            for (int jr = 0; jr < 3; ++jr)
#pragma unroll
                for (int i = 0; i < 3; ++i) {
                    const int d = jr * 3 + i;
                    const float u0 = (rv[jr] && cv[i])     ? q2[rows[jr] + cols[i]]     : 0.f;
                    const float u1 = (rv[jr + 3] && cv[i]) ? q2[rows[jr + 3] + cols[i]] : 0.f;
                    acc[0][d] = fmaf(a0, u0, acc[0][d]);
                    acc[1][d] = fmaf(a1, u1, acc[1][d]);
                }
            q1 += plane; q2 += plane;
        }
    }
    __shared__ float rl[9][16][32];
#pragma unroll
    for (int d = 0; d < 9; ++d) {
        rl[d][ty][tx]     = acc[0][d];
        rl[d][ty + 8][tx] = acc[1][d];
    }
    __syncthreads();
    const int tid = ty * 32 + tx;
    for (int j = tid; j < FBTOX * FBTOY; j += 256) {
        const int oy = j / FBTOX, ox = j - oy * FBTOX;
        const int y = y0 + oy, x = x0 + ox;
        if (y < OH && x < OW) {
#pragma unroll
            for (int d = 0; d < 9; ++d) {
                float s = 0.f;
#pragma unroll
                for (int a = 0; a < 3; ++a)
#pragma unroll
                    for (int b2 = 0; b2 < 3; ++b2)
                        s += rl[d][oy + a][ox + b2];
                out[(((size_t)b * 9 + d) * OH + y) * OW + x] = s * (1.0f / 864.0f);
            }
        }
    }
}

extern "C" void kernel_launch(void* const* d_in, const int* in_sizes, int n_in,
                              void* d_out, int out_size, void* d_ws, size_t ws_size,
                              hipStream_t stream) {
    const float* x1 = (const float*)d_in[0];
    const float* x2 = (const float*)d_in[1];
    float* out = (float*)d_out;
    if (ws_size >= WS_NEEDED) {
        float* rws = (float*)d_ws;
        hipLaunchKernelGGL(corr_r_kernel, dim3(NPAIR, BB), dim3(256), 0, stream, x1, x2, rws);
        hipLaunchKernelGGL(corr_box_kernel, dim3(K2_BLOCKS), dim3(256), 0, stream, rws, out);
    } else {
        hipLaunchKernelGGL(corr2d_fb,
                           dim3((OW + FBTOX - 1) / FBTOX, (OH + FBTOY - 1) / FBTOY, BB),
                           dim3(32, 8), 0, stream, x1, x2, out);
    }
}